// Round 18
// baseline (116.713 us; speedup 1.0000x reference)
//
#include <hip/hip_runtime.h>
#include <math.h>

#define DIM 64
#define R_SHIFT 7            // 128 rows per partition
#define R_PART  128
#define CHUNK   2048         // edges per block in ppart (4 per thread, 512 thr)
#define EPT     4
#define PCAP    3072         // fixed bucket capacity per partition (~23 sigma)
#define PCUR_STRIDE 16       // pad partition cursors to one per 64B line

typedef __attribute__((ext_vector_type(8))) short bf16x8;
typedef __attribute__((ext_vector_type(4))) float f32x4;

static __device__ inline unsigned short f32_to_bf16(float f) {
    unsigned u = __float_as_uint(f);
    u += 0x7FFFu + ((u >> 16) & 1u);   // round-to-nearest-even
    return (unsigned short)(u >> 16);
}
static __device__ inline float bf16_to_f32(unsigned short h) {
    return __uint_as_float((unsigned)h << 16);
}

// packed 4-byte edge entry: [31:25]=row&127, [24:8]=col (17b), [7:0]=q8
// In tmp: q8 = sim_weight (in [0,1)). After pgather2 pass-2: q8 = coef.
static __device__ inline unsigned pack_entry4(int r, int c, float v) {
    int q = (int)(v * 256.0f + 0.5f);
    if (q > 255) q = 255;
    return ((unsigned)(r & (R_PART - 1)) << 25) | ((unsigned)c << 8) | (unsigned)q;
}
static __device__ inline int e_col(unsigned e)  { return (int)((e >> 8) & 0x1FFFFu); }
static __device__ inline float e_q8(unsigned e) {
    return (float)(e & 0xFFu) * 0.00390625f;   // q / 256
}

// ---------------------------------------------------------------------------
// K1 (MFMA, r17-verified): hxb = bf16(x @ W);
// selfb = bf16(sigmoid(rep)*(x @ W_self)); repns[row] = (rep,ns) packed.
// ---------------------------------------------------------------------------
__global__ __launch_bounds__(256) void gemm_dual_mfma(
        const float* __restrict__ x,
        const float* __restrict__ W,
        const float* __restrict__ Wself,
        const float* __restrict__ rep,
        const float* __restrict__ ns,
        unsigned short* __restrict__ hxb,
        unsigned short* __restrict__ selfb,
        float2* __restrict__ repns, int n) {
    __shared__ __align__(16) unsigned short xsb[64][72];
    __shared__ __align__(16) unsigned short Wtb[64][72];   // Wtb[col][k]
    __shared__ __align__(16) unsigned short Vtb[64][72];

    const int t = threadIdx.x;
    const int row0 = blockIdx.x * 64;

    // stage W, W_self transposed -> bf16 (coalesced global reads)
    for (int i = t; i < 4096; i += 256) {
        int r = i >> 6, c = i & 63;
        Wtb[c][r] = f32_to_bf16(W[i]);
        Vtb[c][r] = f32_to_bf16(Wself[i]);
    }
    // stage x tile -> bf16 (vectorized reads), zero-pad rows beyond n
    for (int i = t; i < 1024; i += 256) {
        int r = i >> 4, c4 = i & 15;
        float4 v = make_float4(0.f, 0.f, 0.f, 0.f);
        if (row0 + r < n) v = ((const float4*)x)[(size_t)(row0 + r) * 16 + c4];
        ushort4 b;
        b.x = f32_to_bf16(v.x); b.y = f32_to_bf16(v.y);
        b.z = f32_to_bf16(v.z); b.w = f32_to_bf16(v.w);
        *(ushort4*)&xsb[r][c4 * 4] = b;
    }
    // repns side-product (coalesced)
    if (t < 64) {
        int row = row0 + t;
        if (row < n) repns[row] = make_float2(rep[row], ns[row]);
    }
    __syncthreads();

    const int lane = t & 63;
    const int wave = t >> 6;
    const int lr = lane & 15;     // A row-in-tile / B,D col-in-tile
    const int kg = lane >> 4;     // k-group 0..3

    bf16x8 a0 = *(const bf16x8*)&xsb[wave * 16 + lr][kg * 8];        // k 0..31
    bf16x8 a1 = *(const bf16x8*)&xsb[wave * 16 + lr][32 + kg * 8];   // k 32..63

    f32x4 accw[4], accv[4];
#pragma unroll
    for (int ct = 0; ct < 4; ++ct) {
        accw[ct] = (f32x4){0.f, 0.f, 0.f, 0.f};
        accv[ct] = (f32x4){0.f, 0.f, 0.f, 0.f};
    }

#pragma unroll
    for (int ct = 0; ct < 4; ++ct) {
        bf16x8 bw0 = *(const bf16x8*)&Wtb[ct * 16 + lr][kg * 8];
        bf16x8 bw1 = *(const bf16x8*)&Wtb[ct * 16 + lr][32 + kg * 8];
        bf16x8 bv0 = *(const bf16x8*)&Vtb[ct * 16 + lr][kg * 8];
        bf16x8 bv1 = *(const bf16x8*)&Vtb[ct * 16 + lr][32 + kg * 8];
        accw[ct] = __builtin_amdgcn_mfma_f32_16x16x32_bf16(a0, bw0, accw[ct], 0, 0, 0);
        accw[ct] = __builtin_amdgcn_mfma_f32_16x16x32_bf16(a1, bw1, accw[ct], 0, 0, 0);
        accv[ct] = __builtin_amdgcn_mfma_f32_16x16x32_bf16(a0, bv0, accv[ct], 0, 0, 0);
        accv[ct] = __builtin_amdgcn_mfma_f32_16x16x32_bf16(a1, bv1, accv[ct], 0, 0, 0);
    }

    // D[row = wave*16 + kg*4 + j][col = ct*16 + lr]
#pragma unroll
    for (int j = 0; j < 4; ++j) {
        int row = row0 + wave * 16 + kg * 4 + j;
        if (row >= n) continue;
        float srep = 1.0f / (1.0f + __expf(-rep[row]));
#pragma unroll
        for (int ct = 0; ct < 4; ++ct) {
            int col = ct * 16 + lr;
            hxb[(size_t)row * DIM + col]   = f32_to_bf16(accw[ct][j]);
            selfb[(size_t)row * DIM + col] = f32_to_bf16(srep * accv[ct][j]);
        }
    }
}

// ---------------------------------------------------------------------------
// ppart (pure ROUTER, r16-verified): partition edges into fixed buckets
// tmp[p*PCAP + slot]. ZERO gathers: ei/sw reads coalesced; entry carries sw-q8.
// LDS rank + one padded global atomic per (block, partition).
// ---------------------------------------------------------------------------
__global__ __launch_bounds__(512) void ppart_kernel(
        const int* __restrict__ ei,
        const float* __restrict__ sw,
        int* __restrict__ pcur,          // padded: pcur[p * PCUR_STRIDE]
        unsigned* __restrict__ tmp, int E, int NP) {
    __shared__ int cnt[1024];
    __shared__ int gb[1024];
    for (int p = threadIdx.x; p < NP; p += 512) cnt[p] = 0;
    __syncthreads();

    const int base = blockIdx.x * CHUNK;

    int r_[EPT], c_[EPT]; float sw_[EPT];
#pragma unroll
    for (int i = 0; i < EPT; ++i) {
        int e = base + i * 512 + threadIdx.x;
        bool v = (e < E);
        r_[i]  = v ? ei[e] : -1;
        c_[i]  = v ? ei[E + e] : 0;
        sw_[i] = v ? sw[e] : 0.f;
    }

    int pid[EPT]; int rank[EPT]; unsigned pay[EPT];
#pragma unroll
    for (int i = 0; i < EPT; ++i) {
        pid[i] = -1;
        if (r_[i] >= 0) {
            pid[i]  = r_[i] >> R_SHIFT;
            pay[i]  = pack_entry4(r_[i], c_[i], sw_[i]);
            rank[i] = atomicAdd(&cnt[pid[i]], 1);
        }
    }
    __syncthreads();

    const int off = (int)((blockIdx.x * 387u) % (unsigned)NP);
    for (int q = threadIdx.x; q < NP; q += 512) {
        int p = q + off; if (p >= NP) p -= NP;
        int c = cnt[p];
        gb[p] = c ? atomicAdd(&pcur[p * PCUR_STRIDE], c) : 0;
    }
    __syncthreads();

#pragma unroll
    for (int i = 0; i < EPT; ++i)
        if (pid[i] >= 0) {
            int s = gb[pid[i]] + rank[i];
            if (s < PCAP)   // ~23-sigma guard; statistically never taken
                tmp[(size_t)pid[i] * PCAP + s] = pay[i];
        }
}

// ---------------------------------------------------------------------------
// pgather2: LDS counting sort + register-accumulate gather. Pass-2 computes
// coef ONCE PER EDGE (single thread): rep[r] from LDS, (rep,ns)[c] one 8B
// L2-hot load, sigmoid once, re-pack q8. Gather loop unchanged (r15-verified).
// ---------------------------------------------------------------------------
template<int K>
__device__ inline void lgather_k(const unsigned* __restrict__ sorted, int j,
                                 const unsigned short* __restrict__ hxb,
                                 int lane, float& acc) {
    unsigned e[K]; unsigned short h[K];
#pragma unroll
    for (int i = 0; i < K; ++i) e[i] = sorted[j + i];   // LDS broadcast reads
#pragma unroll
    for (int i = 0; i < K; ++i) h[i] = hxb[(size_t)e_col(e[i]) * DIM + lane];
#pragma unroll
    for (int i = 0; i < K; ++i) acc = fmaf(e_q8(e[i]), bf16_to_f32(h[i]), acc);
}

__global__ __launch_bounds__(512) void pgather2_kernel(
        const int* __restrict__ pcur,
        const unsigned* __restrict__ tmp,
        const unsigned short* __restrict__ hxb,
        const unsigned short* __restrict__ selfb,
        const float* __restrict__ rep,
        const float2* __restrict__ repns,
        float* __restrict__ out, int n) {
    __shared__ unsigned sorted[PCAP];      // 12 KB entries, row-sorted
    __shared__ float rrep[R_PART];
    __shared__ int rbase[R_PART + 1];
    __shared__ int rcnt[R_PART];
    __shared__ int rcur[R_PART];

    const int p   = blockIdx.x;
    const int tid = threadIdx.x;
    const size_t start = (size_t)p * PCAP;
    const int gbase = p << R_SHIFT;
    int cnt = pcur[p * PCUR_STRIDE];
    if (cnt > PCAP) cnt = PCAP;

    if (tid < R_PART) {
        rcnt[tid] = 0;
        int g = gbase + tid;
        rrep[tid] = (g < n) ? rep[g] : 0.f;
    }
    __syncthreads();

    // pass 1: count rows
    for (int i = tid; i < cnt; i += 512)
        atomicAdd(&rcnt[tmp[start + i] >> 25], 1);
    __syncthreads();

    // wave-0 exclusive scan over 128 counters
    if (tid < 64) {
        int c0 = rcnt[2 * tid], c1 = rcnt[2 * tid + 1];
        int s = c0 + c1;
        int inc = s;
#pragma unroll
        for (int off = 1; off < 64; off <<= 1) {
            int t = __shfl_up(inc, off, 64);
            if (tid >= off) inc += t;
        }
        int excl = inc - s;
        rbase[2 * tid]     = excl;
        rbase[2 * tid + 1] = excl + c0;
        rcur[2 * tid]      = excl;
        rcur[2 * tid + 1]  = excl + c0;
        if (tid == 63) rbase[R_PART] = inc;
    }
    __syncthreads();

    // pass 2: place entries row-sorted; compute coef once per edge.
    for (int i = tid; i < cnt; i += 512) {
        unsigned e = tmp[start + i];
        int row = (int)(e >> 25);
        int c   = e_col(e);
        float2 rn = repns[c];                             // one 8B L2-hot load
        float gate = 1.0f / (1.0f + __expf(-(rrep[row] + rn.x)));
        float coef = e_q8(e) * gate * rn.y;
        int q = (int)(coef * 256.0f + 0.5f);
        if (q > 255) q = 255;
        int slot = atomicAdd(&rcur[row], 1);
        sorted[slot] = (e & 0xFFFFFF00u) | (unsigned)q;
    }
    __syncthreads();

    // per-row register-accumulate gather + fused epilogue (8 waves x 16 rows)
    const int lane = tid & 63;
    const int w    = tid >> 6;
    for (int r = w; r < R_PART; r += 8) {
        int g = gbase + r;
        if (g >= n) continue;
        const int b0 = rbase[r], b1 = rbase[r + 1];
        float acc = 0.0f;
        int j = b0;
        for (; j + 8 <= b1; j += 8) lgather_k<8>(sorted, j, hxb, lane, acc);
        if (j + 4 <= b1) { lgather_k<4>(sorted, j, hxb, lane, acc); j += 4; }
        if (j + 2 <= b1) { lgather_k<2>(sorted, j, hxb, lane, acc); j += 2; }
        if (j < b1)      { lgather_k<1>(sorted, j, hxb, lane, acc); }

        float d = (float)(b1 - b0);
        float self = bf16_to_f32(selfb[(size_t)g * DIM + lane]);
        float v = acc / (d + 1e-6f) + self;
        out[(size_t)g * DIM + lane] = (v > 0.f) ? v : 0.01f * v;
    }
}

// ---------------------------------------------------------------------------
// Fallback (small ws): atomic-scatter path (f32 hx).
// ---------------------------------------------------------------------------
__global__ void gemm64_kernel(const float* __restrict__ x,
                              const float* __restrict__ W,
                              float* __restrict__ hx, int n) {
    __shared__ float Ws[DIM * DIM];
    for (int i = threadIdx.x; i < DIM * DIM; i += blockDim.x) Ws[i] = W[i];
    __syncthreads();
    const int lane = threadIdx.x & 63;
    const int wave = threadIdx.x >> 6;
    const int wpb  = blockDim.x >> 6;
    for (int row = blockIdx.x * wpb + wave; row < n; row += gridDim.x * wpb) {
        float xv = x[(size_t)row * DIM + lane];
        float acc = 0.0f;
#pragma unroll
        for (int k = 0; k < 64; ++k)
            acc = fmaf(__shfl(xv, k, 64), Ws[k * DIM + lane], acc);
        hx[(size_t)row * DIM + lane] = acc;
    }
}

__global__ void edge_scatter_kernel(const int* __restrict__ ei,
                                    const float* __restrict__ sw,
                                    const float* __restrict__ rep,
                                    const float* __restrict__ ns,
                                    const float* __restrict__ hx,
                                    float* __restrict__ out,
                                    float* __restrict__ deg, int E) {
    long long t = (long long)blockIdx.x * blockDim.x + threadIdx.x;
    int e = (int)(t >> 6);
    int d = (int)(t & 63);
    if (e >= E) return;
    int r = ei[e];
    int c = ei[E + e];
    float gate = 1.0f / (1.0f + __expf(-(rep[r] + rep[c])));
    float coef = sw[e] * gate * ns[c];
    atomicAdd(&out[(size_t)r * DIM + d], coef * hx[(size_t)c * DIM + d]);
    if (d == 0) atomicAdd(&deg[r], 1.0f);
}

__global__ void finalize_kernel(const float* __restrict__ x,
                                const float* __restrict__ Wself,
                                const float* __restrict__ rep,
                                const float* __restrict__ deg,
                                float* __restrict__ out, int n) {
    __shared__ float Ws[DIM * DIM];
    for (int i = threadIdx.x; i < DIM * DIM; i += blockDim.x) Ws[i] = Wself[i];
    __syncthreads();
    const int lane = threadIdx.x & 63;
    const int wave = threadIdx.x >> 6;
    const int wpb  = blockDim.x >> 6;
    for (int row = blockIdx.x * wpb + wave; row < n; row += gridDim.x * wpb) {
        float xv = x[(size_t)row * DIM + lane];
        float self = 0.0f;
#pragma unroll
        for (int k = 0; k < 64; ++k)
            self = fmaf(__shfl(xv, k, 64), Ws[k * DIM + lane], self);
        float srep = 1.0f / (1.0f + __expf(-rep[row]));
        float v = out[(size_t)row * DIM + lane] / (deg[row] + 1e-6f) + srep * self;
        out[(size_t)row * DIM + lane] = (v > 0.0f) ? v : 0.01f * v;
    }
}

// ---------------------------------------------------------------------------
extern "C" void kernel_launch(void* const* d_in, const int* in_sizes, int n_in,
                              void* d_out, int out_size, void* d_ws, size_t ws_size,
                              hipStream_t stream) {
    const float* x     = (const float*)d_in[0];
    const int*   ei    = (const int*)d_in[1];
    const float* sw    = (const float*)d_in[2];
    const float* rep   = (const float*)d_in[3];
    const float* ns    = (const float*)d_in[4];
    const float* W     = (const float*)d_in[5];
    const float* Wself = (const float*)d_in[6];

    const int n = in_sizes[0] / DIM;   // 100000
    const int E = in_sizes[2];         // 1600000

    float* out = (float*)d_out;
    char*  ws  = (char*)d_ws;

    const int NP = (n + R_PART - 1) >> R_SHIFT;   // 782 partitions

    size_t off = 0;
    unsigned short* hxb   = (unsigned short*)(ws + off); off += (size_t)n * DIM * 2;  // 12.8 MB
    unsigned short* selfb = (unsigned short*)(ws + off); off += (size_t)n * DIM * 2;  // 12.8 MB
    float2* repns = (float2*)(ws + off); off += (size_t)n * 8;                        // 0.8 MB
    unsigned* tmp = (unsigned*)(ws + off); off += (size_t)NP * PCAP * 4;              // 9.6 MB
    int*   pcur  = (int*)(ws + off);   off += (size_t)NP * PCUR_STRIDE * 4;           // 50 KB
    const size_t need = off;

    const int NBLK = (E + CHUNK - 1) / CHUNK;          // 782 ppart blocks

    if (ws_size >= need && NP <= 1024) {
        hipMemsetAsync(pcur, 0, (size_t)NP * PCUR_STRIDE * sizeof(int), stream);

        gemm_dual_mfma<<<(n + 63) / 64, 256, 0, stream>>>(
            x, W, Wself, rep, ns, hxb, selfb, repns, n);

        ppart_kernel<<<NBLK, 512, 0, stream>>>(ei, sw, pcur, tmp, E, NP);

        pgather2_kernel<<<NP, 512, 0, stream>>>(pcur, tmp, hxb, selfb,
                                                rep, repns, out, n);
    } else {
        float* hx2 = (float*)ws;
        float* deg = (float*)ws + (size_t)n * DIM;
        hipMemsetAsync(d_out, 0, (size_t)out_size * sizeof(float), stream);
        hipMemsetAsync(deg, 0, (size_t)n * sizeof(float), stream);
        {
            const int block = 256, wpb = block / 64;
            gemm64_kernel<<<(n + wpb - 1) / wpb, block, 0, stream>>>(x, W, hx2, n);
        }
        {
            long long total = (long long)E * DIM;
            edge_scatter_kernel<<<(int)((total + 255) / 256), 256, 0, stream>>>(
                ei, sw, rep, ns, hx2, out, deg, E);
        }
        {
            const int block = 256, wpb = block / 64;
            finalize_kernel<<<(n + wpb - 1) / wpb, block, 0, stream>>>(
                x, Wself, rep, deg, out, n);
        }
    }
}

// Round 19
// 111.292 us; speedup vs baseline: 1.0487x; 1.0487x over previous
//
#include <hip/hip_runtime.h>
#include <math.h>

#define DIM 64
#define R_SHIFT 7            // 128 rows per partition
#define R_PART  128
#define CHUNK   4096         // edges per block in ppart (8 per thread, 512 thr)
#define EPT     8
#define CAP     4096         // sort buffer entries in pgather2
#define PCAP    3072         // fixed bucket capacity per partition (~23 sigma)
#define PCUR_STRIDE 16       // pad partition cursors to one per 64B line

typedef __attribute__((ext_vector_type(8))) short bf16x8;
typedef __attribute__((ext_vector_type(4))) float f32x4;

static __device__ inline unsigned short f32_to_bf16(float f) {
    unsigned u = __float_as_uint(f);
    u += 0x7FFFu + ((u >> 16) & 1u);   // round-to-nearest-even
    return (unsigned short)(u >> 16);
}
static __device__ inline float bf16_to_f32(unsigned short h) {
    return __uint_as_float((unsigned)h << 16);
}

// packed 4-byte edge entry: [31:25]=row&127, [24:8]=col (17b), [7:0]=coef q8
// coef = sw*gate*ns in [0,1): fixed-point 8-bit, abs err <= 2^-9.
static __device__ inline unsigned pack_entry4(int r, int c, float coef) {
    int q = (int)(coef * 256.0f + 0.5f);
    if (q > 255) q = 255;
    return ((unsigned)(r & (R_PART - 1)) << 25) | ((unsigned)c << 8) | (unsigned)q;
}
static __device__ inline int e_col(unsigned e)  { return (int)((e >> 8) & 0x1FFFFu); }
static __device__ inline float e_coef(unsigned e) {
    return (float)(e & 0xFFu) * 0.00390625f;   // q / 256
}

// ---------------------------------------------------------------------------
// K1 (MFMA, r17-verified): hxb = bf16(x @ W);
// selfb = bf16(sigmoid(rep)*(x @ W_self)).
// Block = 256 thr = 4 waves = one 64-row tile; per wave 16x
// mfma_f32_16x16x32_bf16. Fragment maps (guide-verified):
// A[row=lane&15][k=8*(lane>>4)+i]; B[k=8*(lane>>4)+i][col=lane&15];
// D[row=(lane>>4)*4+j][col=lane&15].
// ---------------------------------------------------------------------------
__global__ __launch_bounds__(256) void gemm_dual_mfma(
        const float* __restrict__ x,
        const float* __restrict__ W,
        const float* __restrict__ Wself,
        const float* __restrict__ rep,
        unsigned short* __restrict__ hxb,
        unsigned short* __restrict__ selfb, int n) {
    __shared__ __align__(16) unsigned short xsb[64][72];
    __shared__ __align__(16) unsigned short Wtb[64][72];   // Wtb[col][k]
    __shared__ __align__(16) unsigned short Vtb[64][72];

    const int t = threadIdx.x;
    const int row0 = blockIdx.x * 64;

    // stage W, W_self transposed -> bf16 (coalesced global reads)
    for (int i = t; i < 4096; i += 256) {
        int r = i >> 6, c = i & 63;
        Wtb[c][r] = f32_to_bf16(W[i]);
        Vtb[c][r] = f32_to_bf16(Wself[i]);
    }
    // stage x tile -> bf16 (vectorized reads), zero-pad rows beyond n
    for (int i = t; i < 1024; i += 256) {
        int r = i >> 4, c4 = i & 15;
        float4 v = make_float4(0.f, 0.f, 0.f, 0.f);
        if (row0 + r < n) v = ((const float4*)x)[(size_t)(row0 + r) * 16 + c4];
        ushort4 b;
        b.x = f32_to_bf16(v.x); b.y = f32_to_bf16(v.y);
        b.z = f32_to_bf16(v.z); b.w = f32_to_bf16(v.w);
        *(ushort4*)&xsb[r][c4 * 4] = b;
    }
    __syncthreads();

    const int lane = t & 63;
    const int wave = t >> 6;
    const int lr = lane & 15;     // A row-in-tile / B,D col-in-tile
    const int kg = lane >> 4;     // k-group 0..3

    bf16x8 a0 = *(const bf16x8*)&xsb[wave * 16 + lr][kg * 8];        // k 0..31
    bf16x8 a1 = *(const bf16x8*)&xsb[wave * 16 + lr][32 + kg * 8];   // k 32..63

    f32x4 accw[4], accv[4];
#pragma unroll
    for (int ct = 0; ct < 4; ++ct) {
        accw[ct] = (f32x4){0.f, 0.f, 0.f, 0.f};
        accv[ct] = (f32x4){0.f, 0.f, 0.f, 0.f};
    }

#pragma unroll
    for (int ct = 0; ct < 4; ++ct) {
        bf16x8 bw0 = *(const bf16x8*)&Wtb[ct * 16 + lr][kg * 8];
        bf16x8 bw1 = *(const bf16x8*)&Wtb[ct * 16 + lr][32 + kg * 8];
        bf16x8 bv0 = *(const bf16x8*)&Vtb[ct * 16 + lr][kg * 8];
        bf16x8 bv1 = *(const bf16x8*)&Vtb[ct * 16 + lr][32 + kg * 8];
        accw[ct] = __builtin_amdgcn_mfma_f32_16x16x32_bf16(a0, bw0, accw[ct], 0, 0, 0);
        accw[ct] = __builtin_amdgcn_mfma_f32_16x16x32_bf16(a1, bw1, accw[ct], 0, 0, 0);
        accv[ct] = __builtin_amdgcn_mfma_f32_16x16x32_bf16(a0, bv0, accv[ct], 0, 0, 0);
        accv[ct] = __builtin_amdgcn_mfma_f32_16x16x32_bf16(a1, bv1, accv[ct], 0, 0, 0);
    }

    // D[row = wave*16 + kg*4 + j][col = ct*16 + lr]
#pragma unroll
    for (int j = 0; j < 4; ++j) {
        int row = row0 + wave * 16 + kg * 4 + j;
        if (row >= n) continue;
        float srep = 1.0f / (1.0f + __expf(-rep[row]));
#pragma unroll
        for (int ct = 0; ct < 4; ++ct) {
            int col = ct * 16 + lr;
            hxb[(size_t)row * DIM + col]   = f32_to_bf16(accw[ct][j]);
            selfb[(size_t)row * DIM + col] = f32_to_bf16(srep * accv[ct][j]);
        }
    }
}

// ---------------------------------------------------------------------------
// ppart (r15-verified): partition edges into fixed buckets tmp[p*PCAP+slot].
// Computes coef once per edge (rep/ns gathers are L2-hot). LDS rank + one
// padded global atomic per (block, partition) reservation.
// ---------------------------------------------------------------------------
__global__ __launch_bounds__(512) void ppart_kernel(
        const int* __restrict__ ei,
        const float* __restrict__ sw,
        const float* __restrict__ rep,
        const float* __restrict__ ns,
        int* __restrict__ pcur,          // padded: pcur[p * PCUR_STRIDE]
        unsigned* __restrict__ tmp, int E, int NP) {
    __shared__ int cnt[1024];
    __shared__ int gb[1024];
    for (int p = threadIdx.x; p < NP; p += 512) cnt[p] = 0;
    __syncthreads();

    const int base = blockIdx.x * CHUNK;

    int r_[EPT], c_[EPT]; float sw_[EPT];
#pragma unroll
    for (int i = 0; i < EPT; ++i) {
        int e = base + i * 512 + threadIdx.x;
        bool v = (e < E);
        r_[i]  = v ? ei[e] : -1;
        c_[i]  = v ? ei[E + e] : 0;
        sw_[i] = v ? sw[e] : 0.f;
    }

    float repr[EPT], repc[EPT], nsc[EPT];
#pragma unroll
    for (int i = 0; i < EPT; ++i) {
        int rr = (r_[i] >= 0) ? r_[i] : 0;
        repr[i] = rep[rr];
        repc[i] = rep[c_[i]];
        nsc[i]  = ns[c_[i]];
    }

    int pid[EPT]; int rank[EPT]; unsigned pay[EPT];
#pragma unroll
    for (int i = 0; i < EPT; ++i) {
        pid[i] = -1;
        if (r_[i] >= 0) {
            float gate = 1.0f / (1.0f + __expf(-(repr[i] + repc[i])));
            float coef = sw_[i] * gate * nsc[i];
            pid[i]  = r_[i] >> R_SHIFT;
            pay[i]  = pack_entry4(r_[i], c_[i], coef);
            rank[i] = atomicAdd(&cnt[pid[i]], 1);
        }
    }
    __syncthreads();

    const int off = (int)((blockIdx.x * 387u) % (unsigned)NP);
    for (int q = threadIdx.x; q < NP; q += 512) {
        int p = q + off; if (p >= NP) p -= NP;
        int c = cnt[p];
        gb[p] = c ? atomicAdd(&pcur[p * PCUR_STRIDE], c) : 0;
    }
    __syncthreads();

#pragma unroll
    for (int i = 0; i < EPT; ++i)
        if (pid[i] >= 0) {
            int s = gb[pid[i]] + rank[i];
            if (s < PCAP)   // ~23-sigma guard; statistically never taken
                tmp[(size_t)pid[i] * PCAP + s] = pay[i];
        }
}

// ---------------------------------------------------------------------------
// pgather2 (r15-verified): per-partition LDS counting sort + register-
// accumulate gather. 512 threads. One coalesced write per row.
// ---------------------------------------------------------------------------
template<int K>
__device__ inline void lgather_k(const unsigned* __restrict__ sorted, int j,
                                 const unsigned short* __restrict__ hxb,
                                 int lane, float& acc) {
    unsigned e[K]; unsigned short h[K];
#pragma unroll
    for (int i = 0; i < K; ++i) e[i] = sorted[j + i];   // LDS broadcast reads
#pragma unroll
    for (int i = 0; i < K; ++i) h[i] = hxb[(size_t)e_col(e[i]) * DIM + lane];
#pragma unroll
    for (int i = 0; i < K; ++i) acc = fmaf(e_coef(e[i]), bf16_to_f32(h[i]), acc);
}

__global__ __launch_bounds__(512) void pgather2_kernel(
        const int* __restrict__ pcur,
        const unsigned* __restrict__ tmp,
        const unsigned short* __restrict__ hxb,
        const unsigned short* __restrict__ selfb,
        float* __restrict__ out, int n) {
    __shared__ unsigned sorted[CAP];       // entries, row-sorted
    __shared__ int rbase[R_PART + 1];
    __shared__ int rcnt[R_PART];
    __shared__ int rcur[R_PART];

    const int p   = blockIdx.x;
    const int tid = threadIdx.x;
    const size_t start = (size_t)p * PCAP;
    int cnt = pcur[p * PCUR_STRIDE];
    if (cnt > PCAP) cnt = PCAP;

    if (tid < R_PART) rcnt[tid] = 0;
    __syncthreads();

    // pass 1: count rows
    for (int i = tid; i < cnt; i += 512)
        atomicAdd(&rcnt[tmp[start + i] >> 25], 1);
    __syncthreads();

    // wave-0 exclusive scan over 128 counters
    if (tid < 64) {
        int c0 = rcnt[2 * tid], c1 = rcnt[2 * tid + 1];
        int s = c0 + c1;
        int inc = s;
#pragma unroll
        for (int off = 1; off < 64; off <<= 1) {
            int t = __shfl_up(inc, off, 64);
            if (tid >= off) inc += t;
        }
        int excl = inc - s;
        rbase[2 * tid]     = excl;
        rbase[2 * tid + 1] = excl + c0;
        rcur[2 * tid]      = excl;
        rcur[2 * tid + 1]  = excl + c0;
        if (tid == 63) rbase[R_PART] = inc;
    }
    __syncthreads();

    // pass 2: place entries row-sorted (tmp re-read is L2-hit)
    for (int i = tid; i < cnt; i += 512) {
        unsigned e = tmp[start + i];
        int slot = atomicAdd(&rcur[e >> 25], 1);
        sorted[slot] = e;
    }
    __syncthreads();

    // per-row register-accumulate gather + fused epilogue (8 waves x 16 rows)
    const int lane = tid & 63;
    const int w    = tid >> 6;
    const int gbase = p << R_SHIFT;
    for (int r = w; r < R_PART; r += 8) {
        int g = gbase + r;
        if (g >= n) continue;
        const int b0 = rbase[r], b1 = rbase[r + 1];
        float acc = 0.0f;
        int j = b0;
        for (; j + 8 <= b1; j += 8) lgather_k<8>(sorted, j, hxb, lane, acc);
        if (j + 4 <= b1) { lgather_k<4>(sorted, j, hxb, lane, acc); j += 4; }
        if (j + 2 <= b1) { lgather_k<2>(sorted, j, hxb, lane, acc); j += 2; }
        if (j < b1)      { lgather_k<1>(sorted, j, hxb, lane, acc); }

        float d = (float)(b1 - b0);
        float self = bf16_to_f32(selfb[(size_t)g * DIM + lane]);
        float v = acc / (d + 1e-6f) + self;
        out[(size_t)g * DIM + lane] = (v > 0.f) ? v : 0.01f * v;
    }
}

// ---------------------------------------------------------------------------
// Fallback (small ws): atomic-scatter path (f32 hx).
// ---------------------------------------------------------------------------
__global__ void gemm64_kernel(const float* __restrict__ x,
                              const float* __restrict__ W,
                              float* __restrict__ hx, int n) {
    __shared__ float Ws[DIM * DIM];
    for (int i = threadIdx.x; i < DIM * DIM; i += blockDim.x) Ws[i] = W[i];
    __syncthreads();
    const int lane = threadIdx.x & 63;
    const int wave = threadIdx.x >> 6;
    const int wpb  = blockDim.x >> 6;
    for (int row = blockIdx.x * wpb + wave; row < n; row += gridDim.x * wpb) {
        float xv = x[(size_t)row * DIM + lane];
        float acc = 0.0f;
#pragma unroll
        for (int k = 0; k < 64; ++k)
            acc = fmaf(__shfl(xv, k, 64), Ws[k * DIM + lane], acc);
        hx[(size_t)row * DIM + lane] = acc;
    }
}

__global__ void edge_scatter_kernel(const int* __restrict__ ei,
                                    const float* __restrict__ sw,
                                    const float* __restrict__ rep,
                                    const float* __restrict__ ns,
                                    const float* __restrict__ hx,
                                    float* __restrict__ out,
                                    float* __restrict__ deg, int E) {
    long long t = (long long)blockIdx.x * blockDim.x + threadIdx.x;
    int e = (int)(t >> 6);
    int d = (int)(t & 63);
    if (e >= E) return;
    int r = ei[e];
    int c = ei[E + e];
    float gate = 1.0f / (1.0f + __expf(-(rep[r] + rep[c])));
    float coef = sw[e] * gate * ns[c];
    atomicAdd(&out[(size_t)r * DIM + d], coef * hx[(size_t)c * DIM + d]);
    if (d == 0) atomicAdd(&deg[r], 1.0f);
}

__global__ void finalize_kernel(const float* __restrict__ x,
                                const float* __restrict__ Wself,
                                const float* __restrict__ rep,
                                const float* __restrict__ deg,
                                float* __restrict__ out, int n) {
    __shared__ float Ws[DIM * DIM];
    for (int i = threadIdx.x; i < DIM * DIM; i += blockDim.x) Ws[i] = Wself[i];
    __syncthreads();
    const int lane = threadIdx.x & 63;
    const int wave = threadIdx.x >> 6;
    const int wpb  = blockDim.x >> 6;
    for (int row = blockIdx.x * wpb + wave; row < n; row += gridDim.x * wpb) {
        float xv = x[(size_t)row * DIM + lane];
        float self = 0.0f;
#pragma unroll
        for (int k = 0; k < 64; ++k)
            self = fmaf(__shfl(xv, k, 64), Ws[k * DIM + lane], self);
        float srep = 1.0f / (1.0f + __expf(-rep[row]));
        float v = out[(size_t)row * DIM + lane] / (deg[row] + 1e-6f) + srep * self;
        out[(size_t)row * DIM + lane] = (v > 0.0f) ? v : 0.01f * v;
    }
}

// ---------------------------------------------------------------------------
extern "C" void kernel_launch(void* const* d_in, const int* in_sizes, int n_in,
                              void* d_out, int out_size, void* d_ws, size_t ws_size,
                              hipStream_t stream) {
    const float* x     = (const float*)d_in[0];
    const int*   ei    = (const int*)d_in[1];
    const float* sw    = (const float*)d_in[2];
    const float* rep   = (const float*)d_in[3];
    const float* ns    = (const float*)d_in[4];
    const float* W     = (const float*)d_in[5];
    const float* Wself = (const float*)d_in[6];

    const int n = in_sizes[0] / DIM;   // 100000
    const int E = in_sizes[2];         // 1600000

    float* out = (float*)d_out;
    char*  ws  = (char*)d_ws;

    const int NP = (n + R_PART - 1) >> R_SHIFT;   // 782 partitions

    size_t off = 0;
    unsigned short* hxb   = (unsigned short*)(ws + off); off += (size_t)n * DIM * 2;  // 12.8 MB
    unsigned short* selfb = (unsigned short*)(ws + off); off += (size_t)n * DIM * 2;  // 12.8 MB
    unsigned* tmp = (unsigned*)(ws + off); off += (size_t)NP * PCAP * 4;              // 9.6 MB
    int*   pcur  = (int*)(ws + off);   off += (size_t)NP * PCUR_STRIDE * 4;           // 50 KB
    const size_t need = off;

    const int NBLK = (E + CHUNK - 1) / CHUNK;          // 391 ppart blocks

    if (ws_size >= need && NP <= 1024) {
        hipMemsetAsync(pcur, 0, (size_t)NP * PCUR_STRIDE * sizeof(int), stream);

        gemm_dual_mfma<<<(n + 63) / 64, 256, 0, stream>>>(
            x, W, Wself, rep, hxb, selfb, n);

        ppart_kernel<<<NBLK, 512, 0, stream>>>(ei, sw, rep, ns, pcur, tmp, E, NP);

        pgather2_kernel<<<NP, 512, 0, stream>>>(pcur, tmp, hxb, selfb, out, n);
    } else {
        float* hx2 = (float*)ws;
        float* deg = (float*)ws + (size_t)n * DIM;
        hipMemsetAsync(d_out, 0, (size_t)out_size * sizeof(float), stream);
        hipMemsetAsync(deg, 0, (size_t)n * sizeof(float), stream);
        {
            const int block = 256, wpb = block / 64;
            gemm64_kernel<<<(n + wpb - 1) / wpb, block, 0, stream>>>(x, W, hx2, n);
        }
        {
            long long total = (long long)E * DIM;
            edge_scatter_kernel<<<(int)((total + 255) / 256), 256, 0, stream>>>(
                ei, sw, rep, ns, hx2, out, deg, E);
        }
        {
            const int block = 256, wpb = block / 64;
            finalize_kernel<<<(n + wpb - 1) / wpb, block, 0, stream>>>(
                x, Wself, rep, deg, out, n);
        }
    }
}